// Round 1
// baseline (1859.622 us; speedup 1.0000x reference)
//
#include <hip/hip_runtime.h>
#include <hip/hip_bf16.h>

#define NN 50000
#define EE 800000
#define FIN 256
#define HIDC 128
#define NGRAPH 50

__device__ __forceinline__ float lrelu(float x) { return x > 0.f ? x : 0.2f * x; }

// ---------------- CSR build ----------------
__global__ void hist_kernel(const int* __restrict__ dst, int* __restrict__ deg) {
  int e = blockIdx.x * blockDim.x + threadIdx.x;
  if (e < EE) atomicAdd(&deg[dst[e]], 1);
}

__global__ void scan_kernel(const int* __restrict__ deg, int* __restrict__ indptr,
                            int* __restrict__ cursor) {
  __shared__ int s[1024];
  __shared__ int carry_s;
  if (threadIdx.x == 0) carry_s = 0;
  __syncthreads();
  for (int base = 0; base < NN; base += 1024) {
    int i = base + threadIdx.x;
    int v = (i < NN) ? deg[i] : 0;
    s[threadIdx.x] = v;
    __syncthreads();
    for (int off = 1; off < 1024; off <<= 1) {
      int t = (threadIdx.x >= off) ? s[threadIdx.x - off] : 0;
      __syncthreads();
      s[threadIdx.x] += t;
      __syncthreads();
    }
    int excl = carry_s + s[threadIdx.x] - v;   // exclusive prefix
    if (i < NN) { indptr[i] = excl; cursor[i] = excl; }
    int total = s[1023];
    __syncthreads();
    if (threadIdx.x == 0) carry_s += total;
    __syncthreads();
  }
  if (threadIdx.x == 0) indptr[NN] = carry_s;
}

__global__ void scatter_kernel(const int* __restrict__ src, const int* __restrict__ dst,
                               int* __restrict__ cursor, int* __restrict__ csr_src) {
  int e = blockIdx.x * blockDim.x + threadIdx.x;
  if (e < EE) {
    int d = dst[e];
    int slot = atomicAdd(&cursor[d], 1);
    csr_src[slot] = src[e];
  }
}

// ---------------- f32 tiled GEMM: C[M,Nc] = A[M,K] @ B[K,Nc] ----------------
__global__ __launch_bounds__(256)
void gemm_f32(const float* __restrict__ A, const float* __restrict__ B,
              float* __restrict__ C, int M, int K, int Nc) {
  __shared__ float sA[16][132];   // transposed A tile: sA[k][row]
  __shared__ float sB[16][132];
  const int tid = threadIdx.x;
  const int tx = tid & 15, ty = tid >> 4;
  const int row0 = blockIdx.y * 128, col0 = blockIdx.x * 128;
  float acc[8][8];
#pragma unroll
  for (int i = 0; i < 8; i++)
#pragma unroll
    for (int j = 0; j < 8; j++) acc[i][j] = 0.f;

  for (int k0 = 0; k0 < K; k0 += 16) {
#pragma unroll
    for (int r = 0; r < 2; r++) {
      int id = tid + r * 256;
      int arow = id >> 2, kq = (id & 3) << 2;
      float4 av = make_float4(0.f, 0.f, 0.f, 0.f);
      int grow = row0 + arow;
      if (grow < M) av = *(const float4*)&A[(size_t)grow * K + k0 + kq];
      sA[kq + 0][arow] = av.x;
      sA[kq + 1][arow] = av.y;
      sA[kq + 2][arow] = av.z;
      sA[kq + 3][arow] = av.w;
      int brow = id >> 5, bc = (id & 31) << 2;
      float4 bv = *(const float4*)&B[(size_t)(k0 + brow) * Nc + col0 + bc];
      *(float4*)&sB[brow][bc] = bv;
    }
    __syncthreads();
#pragma unroll
    for (int k = 0; k < 16; k++) {
      float a[8], b[8];
      *(float4*)&a[0] = *(const float4*)&sA[k][ty * 4];
      *(float4*)&a[4] = *(const float4*)&sA[k][64 + ty * 4];
      *(float4*)&b[0] = *(const float4*)&sB[k][tx * 4];
      *(float4*)&b[4] = *(const float4*)&sB[k][64 + tx * 4];
#pragma unroll
      for (int i = 0; i < 8; i++)
#pragma unroll
        for (int j = 0; j < 8; j++) acc[i][j] += a[i] * b[j];
    }
    __syncthreads();
  }
#pragma unroll
  for (int i = 0; i < 8; i++) {
    int grow = row0 + (i < 4 ? ty * 4 + i : 64 + ty * 4 + (i - 4));
    if (grow < M) {
      *(float4*)&C[(size_t)grow * Nc + col0 + tx * 4] = *(float4*)&acc[i][0];
      *(float4*)&C[(size_t)grow * Nc + col0 + 64 + tx * 4] = *(float4*)&acc[i][4];
    }
  }
}

// ---------------- alpha_s / alpha_d: one wave per (node, head) ----------------
template <int H>
__global__ __launch_bounds__(256)
void alpha_kernel(const float* __restrict__ h, const float* __restrict__ a_s,
                  const float* __restrict__ a_d, float* __restrict__ as_out,
                  float* __restrict__ ad_out) {
  int gw = (blockIdx.x * blockDim.x + threadIdx.x) >> 6;
  int lane = threadIdx.x & 63;
  if (gw >= NN * H) return;
  int node = gw / H, hh = gw % H;
  const float2 hv = *(const float2*)&h[(size_t)node * (H * HIDC) + hh * HIDC + lane * 2];
  const float2 sv = *(const float2*)&a_s[hh * HIDC + lane * 2];
  const float2 dv = *(const float2*)&a_d[hh * HIDC + lane * 2];
  float ss = hv.x * sv.x + hv.y * sv.y;
  float sd = hv.x * dv.x + hv.y * dv.y;
#pragma unroll
  for (int off = 32; off; off >>= 1) {
    ss += __shfl_xor(ss, off);
    sd += __shfl_xor(sd, off);
  }
  if (lane == 0) {
    as_out[node * H + hh] = ss;
    ad_out[node * H + hh] = sd;
  }
}

// ---------------- per-dst-node softmax + weighted aggregation ----------------
template <int H, int CH>  // CH = H * HIDC
__global__ __launch_bounds__(256)
void aggregate_kernel(const float* __restrict__ h, const float* __restrict__ asb,
                      const float* __restrict__ adb, const int* __restrict__ indptr,
                      const int* __restrict__ csr_src, const float* __restrict__ bias,
                      float* __restrict__ outp, int applyElu) {
  constexpr int F = CH / 64;  // floats per lane
  int node = (blockIdx.x * blockDim.x + threadIdx.x) >> 6;
  int lane = threadIdx.x & 63;
  if (node >= NN) return;
  int beg = indptr[node], end = indptr[node + 1];
  int deg = end - beg;
  float acc[F];
#pragma unroll
  for (int f = 0; f < F; f++) acc[f] = 0.f;

  if (deg > 0) {
    float adv[H];
#pragma unroll
    for (int hh = 0; hh < H; hh++) adv[hh] = adb[node * H + hh];
    float m[H];
#pragma unroll
    for (int hh = 0; hh < H; hh++) m[hh] = -1e30f;
    for (int i = lane; i < deg; i += 64) {
      int s = csr_src[beg + i];
#pragma unroll
      for (int hh = 0; hh < H; hh++) {
        float e = lrelu(asb[s * H + hh] + adv[hh]);
        m[hh] = fmaxf(m[hh], e);
      }
    }
#pragma unroll
    for (int off = 32; off; off >>= 1)
#pragma unroll
      for (int hh = 0; hh < H; hh++) m[hh] = fmaxf(m[hh], __shfl_xor(m[hh], off));
    float ssum[H];
#pragma unroll
    for (int hh = 0; hh < H; hh++) ssum[hh] = 0.f;
    for (int i = lane; i < deg; i += 64) {
      int s = csr_src[beg + i];
#pragma unroll
      for (int hh = 0; hh < H; hh++) {
        float e = lrelu(asb[s * H + hh] + adv[hh]);
        ssum[hh] += expf(e - m[hh]);
      }
    }
#pragma unroll
    for (int off = 32; off; off >>= 1)
#pragma unroll
      for (int hh = 0; hh < H; hh++) ssum[hh] += __shfl_xor(ssum[hh], off);
    float rden[H];
#pragma unroll
    for (int hh = 0; hh < H; hh++) rden[hh] = 1.f / (ssum[hh] + 1e-16f);

    const int myh = (lane * F) / HIDC;  // this lane's channels live in one head
    float myadv = adv[myh], mym = m[myh], myrd = rden[myh];
    for (int i = 0; i < deg; i++) {
      int s = csr_src[beg + i];
      float e = lrelu(asb[s * H + myh] + myadv);
      float w = expf(e - mym) * myrd;
      const float* hrow = &h[(size_t)s * CH + lane * F];
      if constexpr (F == 8) {
        float4 v0 = *(const float4*)&hrow[0];
        float4 v1 = *(const float4*)&hrow[4];
        acc[0] += w * v0.x; acc[1] += w * v0.y; acc[2] += w * v0.z; acc[3] += w * v0.w;
        acc[4] += w * v1.x; acc[5] += w * v1.y; acc[6] += w * v1.z; acc[7] += w * v1.w;
      } else {
        float2 v0 = *(const float2*)&hrow[0];
        acc[0] += w * v0.x;
        acc[1] += w * v0.y;
      }
    }
  }
#pragma unroll
  for (int f = 0; f < F; f++) {
    int c = lane * F + f;
    float v = acc[f] + bias[c];
    if (applyElu) v = v > 0.f ? v : expm1f(v);
    outp[(size_t)node * CH + c] = v;
  }
}

// ---------------- global mean pool over sorted batch ----------------
__global__ void pool_kernel(const float* __restrict__ node_emb, const int* __restrict__ batch,
                            float* __restrict__ gout) {
  int g = blockIdx.x;
  int c = threadIdx.x;  // 128 threads
  int lo = 0, hi = NN;
  while (lo < hi) { int mid = (lo + hi) >> 1; if (batch[mid] < g) lo = mid + 1; else hi = mid; }
  int s = lo;
  lo = 0; hi = NN;
  while (lo < hi) { int mid = (lo + hi) >> 1; if (batch[mid] < g + 1) lo = mid + 1; else hi = mid; }
  int e = lo;
  float sum = 0.f;
  for (int i = s; i < e; i++) sum += node_emb[(size_t)i * HIDC + c];
  int cnt = e - s;
  gout[g * HIDC + c] = sum / fmaxf((float)cnt, 1.0f);
}

extern "C" void kernel_launch(void* const* d_in, const int* in_sizes, int n_in,
                              void* d_out, int out_size, void* d_ws, size_t ws_size,
                              hipStream_t stream) {
  const float* x   = (const float*)d_in[0];
  const int* ei    = (const int*)d_in[1];
  const int* batch = (const int*)d_in[2];
  const float* W1  = (const float*)d_in[3];
  const float* a1s = (const float*)d_in[4];
  const float* a1d = (const float*)d_in[5];
  const float* b1  = (const float*)d_in[6];
  const float* W2  = (const float*)d_in[7];
  const float* a2s = (const float*)d_in[8];
  const float* a2d = (const float*)d_in[9];
  const float* b2  = (const float*)d_in[10];
  const float* W3  = (const float*)d_in[11];
  const float* a3s = (const float*)d_in[12];
  const float* a3d = (const float*)d_in[13];
  const float* b3  = (const float*)d_in[14];
  float* out_node  = (float*)d_out;
  float* out_graph = out_node + (size_t)NN * HIDC;

  char* p = (char*)d_ws;
  auto take = [&](size_t bytes) {
    char* cur = p;
    p += (bytes + 255) & ~(size_t)255;
    return cur;
  };
  float* buf0 = (float*)take((size_t)NN * 512 * 4);
  float* buf1 = (float*)take((size_t)NN * 512 * 4);
  float* asb  = (float*)take((size_t)NN * 4 * 4);
  float* adb  = (float*)take((size_t)NN * 4 * 4);
  int* deg    = (int*)take((size_t)NN * 4);
  int* indptr = (int*)take((size_t)(NN + 1) * 4);
  int* cursor = (int*)take((size_t)NN * 4);
  int* csr    = (int*)take((size_t)EE * 4);

  const int* srcv = ei;
  const int* dstv = ei + EE;

  // CSR build (per launch; edge_index is restored before every run)
  hipMemsetAsync(deg, 0, (size_t)NN * 4, stream);
  hist_kernel<<<(EE + 255) / 256, 256, 0, stream>>>(dstv, deg);
  scan_kernel<<<1, 1024, 0, stream>>>(deg, indptr, cursor);
  scatter_kernel<<<(EE + 255) / 256, 256, 0, stream>>>(srcv, dstv, cursor, csr);

  dim3 blk(256);
  // layer 1: x[N,256] @ W1[256,512]
  gemm_f32<<<dim3(512 / 128, (NN + 127) / 128), blk, 0, stream>>>(x, W1, buf0, NN, FIN, 512);
  alpha_kernel<4><<<(NN * 4 + 3) / 4, blk, 0, stream>>>(buf0, a1s, a1d, asb, adb);
  aggregate_kernel<4, 512><<<(NN + 3) / 4, blk, 0, stream>>>(buf0, asb, adb, indptr, csr, b1, buf1, 1);
  // layer 2: buf1[N,512] @ W2[512,512]
  gemm_f32<<<dim3(512 / 128, (NN + 127) / 128), blk, 0, stream>>>(buf1, W2, buf0, NN, 512, 512);
  alpha_kernel<4><<<(NN * 4 + 3) / 4, blk, 0, stream>>>(buf0, a2s, a2d, asb, adb);
  aggregate_kernel<4, 512><<<(NN + 3) / 4, blk, 0, stream>>>(buf0, asb, adb, indptr, csr, b2, buf1, 1);
  // layer 3: buf1[N,512] @ W3[512,128]
  gemm_f32<<<dim3(128 / 128, (NN + 127) / 128), blk, 0, stream>>>(buf1, W3, buf0, NN, 512, 128);
  alpha_kernel<1><<<(NN + 3) / 4, blk, 0, stream>>>(buf0, a3s, a3d, asb, adb);
  aggregate_kernel<1, 128><<<(NN + 3) / 4, blk, 0, stream>>>(buf0, asb, adb, indptr, csr, b3, out_node, 0);
  // per-graph mean pool
  pool_kernel<<<NGRAPH, HIDC, 0, stream>>>(out_node, batch, out_graph);
}

// Round 4
// 1408.333 us; speedup vs baseline: 1.3204x; 1.3204x over previous
//
#include <hip/hip_runtime.h>
#include <hip/hip_bf16.h>

#define NN 50000
#define EE 800000
#define FIN 256
#define HIDC 128
#define NGRAPH 50

typedef __attribute__((ext_vector_type(8))) short bf16x8;
typedef __attribute__((ext_vector_type(4))) float f32x4;

__device__ __forceinline__ float lrelu(float x) { return x > 0.f ? x : 0.2f * x; }

__device__ __forceinline__ unsigned short f2bf(float f) {
  union { float f; unsigned u; } c; c.f = f;
  unsigned u = c.u;
  unsigned r = (u + 0x7fffu + ((u >> 16) & 1u)) >> 16;   // RNE
  return (unsigned short)r;
}
__device__ __forceinline__ float bf2f(unsigned short b) {
  union { unsigned u; float f; } c; c.u = ((unsigned)b) << 16;
  return c.f;
}

// ---------------- CSR build ----------------
__global__ void hist_kernel(const int* __restrict__ dst, int* __restrict__ deg) {
  int e = blockIdx.x * blockDim.x + threadIdx.x;
  if (e < EE) atomicAdd(&deg[dst[e]], 1);
}

__global__ void scan_kernel(const int* __restrict__ deg, int* __restrict__ indptr,
                            int* __restrict__ cursor) {
  __shared__ int s[1024];
  __shared__ int carry_s;
  if (threadIdx.x == 0) carry_s = 0;
  __syncthreads();
  for (int base = 0; base < NN; base += 1024) {
    int i = base + threadIdx.x;
    int v = (i < NN) ? deg[i] : 0;
    s[threadIdx.x] = v;
    __syncthreads();
    for (int off = 1; off < 1024; off <<= 1) {
      int t = (threadIdx.x >= off) ? s[threadIdx.x - off] : 0;
      __syncthreads();
      s[threadIdx.x] += t;
      __syncthreads();
    }
    int excl = carry_s + s[threadIdx.x] - v;   // exclusive prefix
    if (i < NN) { indptr[i] = excl; cursor[i] = excl; }
    int total = s[1023];
    __syncthreads();
    if (threadIdx.x == 0) carry_s += total;
    __syncthreads();
  }
  if (threadIdx.x == 0) indptr[NN] = carry_s;
}

__global__ void scatter_kernel(const int* __restrict__ src, const int* __restrict__ dst,
                               int* __restrict__ cursor, int* __restrict__ csr_src) {
  int e = blockIdx.x * blockDim.x + threadIdx.x;
  if (e < EE) {
    int d = dst[e];
    int slot = atomicAdd(&cursor[d], 1);
    csr_src[slot] = src[e];
  }
}

// ---------------- weight transpose + bf16 hi/lo split: W[K][N] -> Wt[N][K] ----------------
__global__ __launch_bounds__(256)
void transpose_split(const float* __restrict__ W, unsigned short* __restrict__ WtHi,
                     unsigned short* __restrict__ WtLo, int K, int N) {
  __shared__ float t[32][33];
  int k0 = blockIdx.y * 32, n0 = blockIdx.x * 32;
  int tx = threadIdx.x & 31, ty = threadIdx.x >> 5;   // ty 0..7
  for (int r = ty; r < 32; r += 8) t[r][tx] = W[(size_t)(k0 + r) * N + n0 + tx];
  __syncthreads();
  for (int r = ty; r < 32; r += 8) {
    float v = t[tx][r];
    unsigned short hb = f2bf(v);
    size_t o = (size_t)(n0 + r) * K + k0 + tx;
    WtHi[o] = hb;
    WtLo[o] = f2bf(v - bf2f(hb));
  }
}

// ---------------- x -> hi/lo split (vectorized by 4) ----------------
__global__ void split_x(const float* __restrict__ in, unsigned short* __restrict__ hi,
                        unsigned short* __restrict__ lo, int n4) {
  int i = blockIdx.x * blockDim.x + threadIdx.x;
  if (i >= n4) return;
  float4 v = ((const float4*)in)[i];
  unsigned short h[4], l[4];
  float a[4] = {v.x, v.y, v.z, v.w};
#pragma unroll
  for (int j = 0; j < 4; j++) { h[j] = f2bf(a[j]); l[j] = f2bf(a[j] - bf2f(h[j])); }
  ((ushort4*)hi)[i] = make_ushort4(h[0], h[1], h[2], h[3]);
  ((ushort4*)lo)[i] = make_ushort4(l[0], l[1], l[2], l[3]);
}

// ---------------- split-bf16 MFMA GEMM: C[M,Nc] = (Ahi+Alo) @ (Bt_hi+Bt_lo)^T ----------------
// A: [M][K] bf16 rows; Bt: [Nc][K] bf16 rows (pre-transposed weights). 3-term split product.
// 128x128 tile, BK=32, 4 waves of 64x64. LDS: 4 sub-tiles [128][32] with chunk XOR swizzle.
__global__ __launch_bounds__(256)
void gemm_split(const unsigned short* __restrict__ Ahi, const unsigned short* __restrict__ Alo,
                const unsigned short* __restrict__ Bhi, const unsigned short* __restrict__ Blo,
                float* __restrict__ C, int M, int K, int Ncols) {
  __shared__ unsigned short smem[4 * 128 * 32];
  const int tid = threadIdx.x;
  const int lane = tid & 63;
  const int wid = tid >> 6;
  const int wr = wid >> 1, wc = wid & 1;
  const int brow0 = blockIdx.y * 128, bcol0 = blockIdx.x * 128;

  f32x4 acc[4][4];
#pragma unroll
  for (int i = 0; i < 4; i++)
#pragma unroll
    for (int j = 0; j < 4; j++) acc[i][j] = (f32x4){0.f, 0.f, 0.f, 0.f};

  for (int k0 = 0; k0 < K; k0 += 32) {
    // stage 4 sub-tiles (Ahi, Alo, Bhi, Blo), each [128][32] bf16, via global_load_lds.
    // LDS dest is linear (slot = tile*512 + s); global source is pre-swizzled so that
    // phys chunk c holds logical chunk c ^ ((row>>1)&3)  (both-sides swizzle, G21).
#pragma unroll
    for (int t = 0; t < 8; t++) {
      const int tile = t >> 1;                    // compile-time per unrolled iter
      const int s = ((t & 1) << 8) + tid;         // slot within tile, 0..511
      const int row = s >> 2;
      const int cl = (s & 3) ^ ((row >> 1) & 3);  // logical 16B chunk to fetch
      const unsigned short* gsrc;
      if (tile < 2) {
        int grow = brow0 + row; if (grow > M - 1) grow = M - 1;
        const unsigned short* base = (tile == 0) ? Ahi : Alo;
        gsrc = base + (size_t)grow * K + k0 + cl * 8;
      } else {
        int gcol = bcol0 + row;
        const unsigned short* base = (tile == 2) ? Bhi : Blo;
        gsrc = base + (size_t)gcol * K + k0 + cl * 8;
      }
      unsigned short* ldst = &smem[(size_t)(tile * 512 + ((t & 1) << 8) + (tid & ~63)) * 8];
      __builtin_amdgcn_global_load_lds((const __attribute__((address_space(1))) void*)gsrc,
                                       (__attribute__((address_space(3))) void*)ldst, 16, 0, 0);
    }
    __syncthreads();

    bf16x8 ah[4], al[4];
#pragma unroll
    for (int mf = 0; mf < 4; mf++) {
      int R = wr * 64 + mf * 16 + (lane & 15);
      int off = R * 32 + ((((lane >> 4)) ^ ((R >> 1) & 3)) << 3);
      ah[mf] = *(const bf16x8*)&smem[off];
      al[mf] = *(const bf16x8*)&smem[4096 + off];
    }
#pragma unroll
    for (int nf = 0; nf < 4; nf++) {
      int R = wc * 64 + nf * 16 + (lane & 15);
      int off = R * 32 + ((((lane >> 4)) ^ ((R >> 1) & 3)) << 3);
      bf16x8 bh = *(const bf16x8*)&smem[8192 + off];
      bf16x8 bl = *(const bf16x8*)&smem[12288 + off];
#pragma unroll
      for (int mf = 0; mf < 4; mf++) {
        acc[mf][nf] = __builtin_amdgcn_mfma_f32_16x16x32_bf16(ah[mf], bh, acc[mf][nf], 0, 0, 0);
        acc[mf][nf] = __builtin_amdgcn_mfma_f32_16x16x32_bf16(al[mf], bh, acc[mf][nf], 0, 0, 0);
        acc[mf][nf] = __builtin_amdgcn_mfma_f32_16x16x32_bf16(ah[mf], bl, acc[mf][nf], 0, 0, 0);
      }
    }
    __syncthreads();
  }

  // epilogue: C/D layout col = lane&15, row = (lane>>4)*4 + reg (m89)
  const int orow = (lane >> 4) * 4;
  const int ocol = lane & 15;
#pragma unroll
  for (int mf = 0; mf < 4; mf++) {
#pragma unroll
    for (int r = 0; r < 4; r++) {
      int grow = brow0 + wr * 64 + mf * 16 + orow + r;
      if (grow < M) {
#pragma unroll
        for (int nf = 0; nf < 4; nf++) {
          int gcol = bcol0 + wc * 64 + nf * 16 + ocol;
          C[(size_t)grow * Ncols + gcol] = acc[mf][nf][r];
        }
      }
    }
  }
}

// ---------------- alpha_s / alpha_d: one wave per (node, head) ----------------
template <int H>
__global__ __launch_bounds__(256)
void alpha_kernel(const float* __restrict__ h, const float* __restrict__ a_s,
                  const float* __restrict__ a_d, float* __restrict__ as_out,
                  float* __restrict__ ad_out) {
  int gw = (blockIdx.x * blockDim.x + threadIdx.x) >> 6;
  int lane = threadIdx.x & 63;
  if (gw >= NN * H) return;
  int node = gw / H, hh = gw % H;
  const float2 hv = *(const float2*)&h[(size_t)node * (H * HIDC) + hh * HIDC + lane * 2];
  const float2 sv = *(const float2*)&a_s[hh * HIDC + lane * 2];
  const float2 dv = *(const float2*)&a_d[hh * HIDC + lane * 2];
  float ss = hv.x * sv.x + hv.y * sv.y;
  float sd = hv.x * dv.x + hv.y * dv.y;
#pragma unroll
  for (int off = 32; off; off >>= 1) {
    ss += __shfl_xor(ss, off);
    sd += __shfl_xor(sd, off);
  }
  if (lane == 0) {
    as_out[node * H + hh] = ss;
    ad_out[node * H + hh] = sd;
  }
}

// ---------------- per-dst-node softmax + weighted aggregation ----------------
template <int H, int CH, bool SPLIT, bool ELU>  // CH = H * HIDC
__global__ __launch_bounds__(256)
void aggregate_kernel(const float* __restrict__ h, const float* __restrict__ asb,
                      const float* __restrict__ adb, const int* __restrict__ indptr,
                      const int* __restrict__ csr_src, const float* __restrict__ bias,
                      float* __restrict__ outF, unsigned short* __restrict__ outHi,
                      unsigned short* __restrict__ outLo) {
  constexpr int F = CH / 64;  // floats per lane
  int node = (blockIdx.x * blockDim.x + threadIdx.x) >> 6;
  int lane = threadIdx.x & 63;
  if (node >= NN) return;
  int beg = indptr[node], end = indptr[node + 1];
  int deg = end - beg;
  float acc[F];
#pragma unroll
  for (int f = 0; f < F; f++) acc[f] = 0.f;

  if (deg > 0) {
    float adv[H];
#pragma unroll
    for (int hh = 0; hh < H; hh++) adv[hh] = adb[node * H + hh];
    float m[H];
#pragma unroll
    for (int hh = 0; hh < H; hh++) m[hh] = -1e30f;
    for (int i = lane; i < deg; i += 64) {
      int s = csr_src[beg + i];
#pragma unroll
      for (int hh = 0; hh < H; hh++) {
        float e = lrelu(asb[s * H + hh] + adv[hh]);
        m[hh] = fmaxf(m[hh], e);
      }
    }
#pragma unroll
    for (int off = 32; off; off >>= 1)
#pragma unroll
      for (int hh = 0; hh < H; hh++) m[hh] = fmaxf(m[hh], __shfl_xor(m[hh], off));
    float ssum[H];
#pragma unroll
    for (int hh = 0; hh < H; hh++) ssum[hh] = 0.f;
    for (int i = lane; i < deg; i += 64) {
      int s = csr_src[beg + i];
#pragma unroll
      for (int hh = 0; hh < H; hh++) {
        float e = lrelu(asb[s * H + hh] + adv[hh]);
        ssum[hh] += expf(e - m[hh]);
      }
    }
#pragma unroll
    for (int off = 32; off; off >>= 1)
#pragma unroll
      for (int hh = 0; hh < H; hh++) ssum[hh] += __shfl_xor(ssum[hh], off);
    float rden[H];
#pragma unroll
    for (int hh = 0; hh < H; hh++) rden[hh] = 1.f / (ssum[hh] + 1e-16f);

    const int myh = (lane * F) / HIDC;  // this lane's channels live in one head
    float myadv = adv[myh], mym = m[myh], myrd = rden[myh];
    for (int i = 0; i < deg; i++) {
      int s = csr_src[beg + i];
      float e = lrelu(asb[s * H + myh] + myadv);
      float w = expf(e - mym) * myrd;
      const float* hrow = &h[(size_t)s * CH + lane * F];
      if constexpr (F == 8) {
        float4 v0 = *(const float4*)&hrow[0];
        float4 v1 = *(const float4*)&hrow[4];
        acc[0] += w * v0.x; acc[1] += w * v0.y; acc[2] += w * v0.z; acc[3] += w * v0.w;
        acc[4] += w * v1.x; acc[5] += w * v1.y; acc[6] += w * v1.z; acc[7] += w * v1.w;
      } else {
        float2 v0 = *(const float2*)&hrow[0];
        acc[0] += w * v0.x;
        acc[1] += w * v0.y;
      }
    }
  }
  if constexpr (SPLIT) {
    unsigned short hs[F], ls[F];
#pragma unroll
    for (int f = 0; f < F; f++) {
      float v = acc[f] + bias[lane * F + f];
      if constexpr (ELU) v = v > 0.f ? v : expm1f(v);
      unsigned short hb = f2bf(v);
      hs[f] = hb;
      ls[f] = f2bf(v - bf2f(hb));
    }
    size_t o = (size_t)node * CH + lane * F;
    *(ushort4*)&outHi[o]     = make_ushort4(hs[0], hs[1], hs[2], hs[3]);
    *(ushort4*)&outHi[o + 4] = make_ushort4(hs[4], hs[5], hs[6], hs[7]);
    *(ushort4*)&outLo[o]     = make_ushort4(ls[0], ls[1], ls[2], ls[3]);
    *(ushort4*)&outLo[o + 4] = make_ushort4(ls[4], ls[5], ls[6], ls[7]);
  } else {
#pragma unroll
    for (int f = 0; f < F; f++) {
      int c = lane * F + f;
      float v = acc[f] + bias[c];
      if constexpr (ELU) v = v > 0.f ? v : expm1f(v);
      outF[(size_t)node * CH + c] = v;
    }
  }
}

// ---------------- global mean pool over sorted batch ----------------
__global__ void pool_kernel(const float* __restrict__ node_emb, const int* __restrict__ batch,
                            float* __restrict__ gout) {
  int g = blockIdx.x;
  int c = threadIdx.x;  // 128 threads
  int lo = 0, hi = NN;
  while (lo < hi) { int mid = (lo + hi) >> 1; if (batch[mid] < g) lo = mid + 1; else hi = mid; }
  int s = lo;
  lo = 0; hi = NN;
  while (lo < hi) { int mid = (lo + hi) >> 1; if (batch[mid] < g + 1) lo = mid + 1; else hi = mid; }
  int e = lo;
  float sum = 0.f;
  for (int i = s; i < e; i++) sum += node_emb[(size_t)i * HIDC + c];
  int cnt = e - s;
  gout[g * HIDC + c] = sum / fmaxf((float)cnt, 1.0f);
}

extern "C" void kernel_launch(void* const* d_in, const int* in_sizes, int n_in,
                              void* d_out, int out_size, void* d_ws, size_t ws_size,
                              hipStream_t stream) {
  const float* x   = (const float*)d_in[0];
  const int* ei    = (const int*)d_in[1];
  const int* batch = (const int*)d_in[2];
  const float* W1  = (const float*)d_in[3];
  const float* a1s = (const float*)d_in[4];
  const float* a1d = (const float*)d_in[5];
  const float* b1  = (const float*)d_in[6];
  const float* W2  = (const float*)d_in[7];
  const float* a2s = (const float*)d_in[8];
  const float* a2d = (const float*)d_in[9];
  const float* b2  = (const float*)d_in[10];
  const float* W3  = (const float*)d_in[11];
  const float* a3s = (const float*)d_in[12];
  const float* a3d = (const float*)d_in[13];
  const float* b3  = (const float*)d_in[14];
  float* out_node  = (float*)d_out;
  float* out_graph = out_node + (size_t)NN * HIDC;

  char* p = (char*)d_ws;
  auto take = [&](size_t bytes) {
    char* cur = p;
    p += (bytes + 255) & ~(size_t)255;
    return cur;
  };
  unsigned short* hHi = (unsigned short*)take((size_t)NN * 512 * 2);
  unsigned short* hLo = (unsigned short*)take((size_t)NN * 512 * 2);
  float* bufF = (float*)take((size_t)NN * 512 * 4);
  float* asb  = (float*)take((size_t)NN * 4 * 4);
  float* adb  = (float*)take((size_t)NN * 4 * 4);
  unsigned short* W1tH = (unsigned short*)take((size_t)512 * 256 * 2);
  unsigned short* W1tL = (unsigned short*)take((size_t)512 * 256 * 2);
  unsigned short* W2tH = (unsigned short*)take((size_t)512 * 512 * 2);
  unsigned short* W2tL = (unsigned short*)take((size_t)512 * 512 * 2);
  unsigned short* W3tH = (unsigned short*)take((size_t)128 * 512 * 2);
  unsigned short* W3tL = (unsigned short*)take((size_t)128 * 512 * 2);
  int* deg    = (int*)take((size_t)NN * 4);
  int* indptr = (int*)take((size_t)(NN + 1) * 4);
  int* cursor = (int*)take((size_t)NN * 4);
  int* csr    = (int*)take((size_t)EE * 4);

  const int* srcv = ei;
  const int* dstv = ei + EE;

  // CSR build
  hipMemsetAsync(deg, 0, (size_t)NN * 4, stream);
  hist_kernel<<<(EE + 255) / 256, 256, 0, stream>>>(dstv, deg);
  scan_kernel<<<1, 1024, 0, stream>>>(deg, indptr, cursor);
  scatter_kernel<<<(EE + 255) / 256, 256, 0, stream>>>(srcv, dstv, cursor, csr);

  // weight transpose + split; x split (x_hi/x_lo alias hHi/hLo — dead before aggregate1 writes)
  transpose_split<<<dim3(512 / 32, 256 / 32), 256, 0, stream>>>(W1, W1tH, W1tL, 256, 512);
  transpose_split<<<dim3(512 / 32, 512 / 32), 256, 0, stream>>>(W2, W2tH, W2tL, 512, 512);
  transpose_split<<<dim3(128 / 32, 512 / 32), 256, 0, stream>>>(W3, W3tH, W3tL, 512, 128);
  split_x<<<(NN * FIN / 4 + 255) / 256, 256, 0, stream>>>(x, hHi, hLo, NN * FIN / 4);

  dim3 blk(256);
  const int rowBlocks = (NN + 127) / 128;
  // layer 1
  gemm_split<<<dim3(4, rowBlocks), blk, 0, stream>>>(hHi, hLo, W1tH, W1tL, bufF, NN, 256, 512);
  alpha_kernel<4><<<(NN * 4 + 3) / 4, blk, 0, stream>>>(bufF, a1s, a1d, asb, adb);
  aggregate_kernel<4, 512, true, true><<<(NN + 3) / 4, blk, 0, stream>>>(
      bufF, asb, adb, indptr, csr, b1, nullptr, hHi, hLo);
  // layer 2
  gemm_split<<<dim3(4, rowBlocks), blk, 0, stream>>>(hHi, hLo, W2tH, W2tL, bufF, NN, 512, 512);
  alpha_kernel<4><<<(NN * 4 + 3) / 4, blk, 0, stream>>>(bufF, a2s, a2d, asb, adb);
  aggregate_kernel<4, 512, true, true><<<(NN + 3) / 4, blk, 0, stream>>>(
      bufF, asb, adb, indptr, csr, b2, nullptr, hHi, hLo);
  // layer 3
  gemm_split<<<dim3(1, rowBlocks), blk, 0, stream>>>(hHi, hLo, W3tH, W3tL, bufF, NN, 512, 128);
  alpha_kernel<1><<<(NN + 3) / 4, blk, 0, stream>>>(bufF, a3s, a3d, asb, adb);
  aggregate_kernel<1, 128, false, false><<<(NN + 3) / 4, blk, 0, stream>>>(
      bufF, asb, adb, indptr, csr, b3, out_node, nullptr, nullptr);
  // per-graph mean pool
  pool_kernel<<<NGRAPH, HIDC, 0, stream>>>(out_node, batch, out_graph);
}

// Round 5
// 1186.313 us; speedup vs baseline: 1.5676x; 1.1872x over previous
//
#include <hip/hip_runtime.h>
#include <hip/hip_bf16.h>

#define NN 50000
#define EE 800000
#define FIN 256
#define HIDC 128
#define NGRAPH 50
#define POOL_CHUNKS 32

typedef __attribute__((ext_vector_type(8))) short bf16x8;
typedef __attribute__((ext_vector_type(4))) float f32x4;

__device__ __forceinline__ float lrelu(float x) { return x > 0.f ? x : 0.2f * x; }

__device__ __forceinline__ unsigned short f2bf(float f) {
  union { float f; unsigned u; } c; c.f = f;
  unsigned u = c.u;
  unsigned r = (u + 0x7fffu + ((u >> 16) & 1u)) >> 16;   // RNE
  return (unsigned short)r;
}
__device__ __forceinline__ float bf2f(unsigned short b) {
  union { unsigned u; float f; } c; c.u = ((unsigned)b) << 16;
  return c.f;
}

// ---------------- CSR build ----------------
__global__ void hist_kernel(const int* __restrict__ dst, int* __restrict__ deg) {
  int e = blockIdx.x * blockDim.x + threadIdx.x;
  if (e < EE) atomicAdd(&deg[dst[e]], 1);
}

// single block, 1024 threads: per-thread serial chunk + wave shuffle scan + LDS wave-sum scan.
__global__ __launch_bounds__(1024)
void scan_kernel(const int* __restrict__ deg, int* __restrict__ indptr,
                 int* __restrict__ cursor) {
  __shared__ int wsum[16];
  const int tid = threadIdx.x;
  const int lane = tid & 63, wid = tid >> 6;
  const int PER = (NN + 1023) / 1024;  // 49
  int base = tid * PER;
  int n = NN - base; if (n < 0) n = 0; if (n > PER) n = PER;
  int sum = 0;
  for (int j = 0; j < n; j++) sum += deg[base + j];
  int inc = sum;
#pragma unroll
  for (int off = 1; off < 64; off <<= 1) {
    int t = __shfl_up(inc, off);
    if (lane >= off) inc += t;
  }
  if (lane == 63) wsum[wid] = inc;
  __syncthreads();
  if (tid == 0) {
    int run = 0;
#pragma unroll
    for (int w = 0; w < 16; w++) { int t = wsum[w]; wsum[w] = run; run += t; }
  }
  __syncthreads();
  int excl = wsum[wid] + inc - sum;   // exclusive prefix of this thread's chunk
  int running = excl;
  for (int j = 0; j < n; j++) {
    int d = deg[base + j];
    indptr[base + j] = running;
    cursor[base + j] = running;
    running += d;
  }
  if (tid == 1023) indptr[NN] = excl + sum;  // n==0 here, excl == grand total
}

__global__ void scatter_kernel(const int* __restrict__ src, const int* __restrict__ dst,
                               int* __restrict__ cursor, int* __restrict__ csr_src) {
  int e = blockIdx.x * blockDim.x + threadIdx.x;
  if (e < EE) {
    int d = dst[e];
    int slot = atomicAdd(&cursor[d], 1);
    csr_src[slot] = src[e];
  }
}

// ---------------- weight transpose + bf16 hi/lo split: W[K][N] -> Wt[N][K] ----------------
__global__ __launch_bounds__(256)
void transpose_split(const float* __restrict__ W, unsigned short* __restrict__ WtHi,
                     unsigned short* __restrict__ WtLo, int K, int N) {
  __shared__ float t[32][33];
  int k0 = blockIdx.y * 32, n0 = blockIdx.x * 32;
  int tx = threadIdx.x & 31, ty = threadIdx.x >> 5;   // ty 0..7
  for (int r = ty; r < 32; r += 8) t[r][tx] = W[(size_t)(k0 + r) * N + n0 + tx];
  __syncthreads();
  for (int r = ty; r < 32; r += 8) {
    float v = t[tx][r];
    unsigned short hb = f2bf(v);
    size_t o = (size_t)(n0 + r) * K + k0 + tx;
    WtHi[o] = hb;
    WtLo[o] = f2bf(v - bf2f(hb));
  }
}

// ---------------- x -> hi/lo split (vectorized by 4) ----------------
__global__ void split_x(const float* __restrict__ in, unsigned short* __restrict__ hi,
                        unsigned short* __restrict__ lo, int n4) {
  int i = blockIdx.x * blockDim.x + threadIdx.x;
  if (i >= n4) return;
  float4 v = ((const float4*)in)[i];
  unsigned short h[4], l[4];
  float a[4] = {v.x, v.y, v.z, v.w};
#pragma unroll
  for (int j = 0; j < 4; j++) { h[j] = f2bf(a[j]); l[j] = f2bf(a[j] - bf2f(h[j])); }
  ((ushort4*)hi)[i] = make_ushort4(h[0], h[1], h[2], h[3]);
  ((ushort4*)lo)[i] = make_ushort4(l[0], l[1], l[2], l[3]);
}

// ---------------- split-bf16 MFMA GEMM: C[M,Nc] = (Ahi+Alo) @ (Bt_hi+Bt_lo)^T ----------------
// A: [M][K] bf16 rows; Bt: [Nc][K] bf16 rows (pre-transposed weights). 3-term split product.
// 128x128 tile, BK=32, 4 waves of 64x64. LDS: 4 sub-tiles [128][32] with chunk XOR swizzle.
__global__ __launch_bounds__(256)
void gemm_split(const unsigned short* __restrict__ Ahi, const unsigned short* __restrict__ Alo,
                const unsigned short* __restrict__ Bhi, const unsigned short* __restrict__ Blo,
                float* __restrict__ C, int M, int K, int Ncols) {
  __shared__ unsigned short smem[4 * 128 * 32];
  const int tid = threadIdx.x;
  const int lane = tid & 63;
  const int wid = tid >> 6;
  const int wr = wid >> 1, wc = wid & 1;
  const int brow0 = blockIdx.y * 128, bcol0 = blockIdx.x * 128;

  f32x4 acc[4][4];
#pragma unroll
  for (int i = 0; i < 4; i++)
#pragma unroll
    for (int j = 0; j < 4; j++) acc[i][j] = (f32x4){0.f, 0.f, 0.f, 0.f};

  for (int k0 = 0; k0 < K; k0 += 32) {
#pragma unroll
    for (int t = 0; t < 8; t++) {
      const int tile = t >> 1;                    // compile-time per unrolled iter
      const int s = ((t & 1) << 8) + tid;         // slot within tile, 0..511
      const int row = s >> 2;
      const int cl = (s & 3) ^ ((row >> 1) & 3);  // logical 16B chunk to fetch
      const unsigned short* gsrc;
      if (tile < 2) {
        int grow = brow0 + row; if (grow > M - 1) grow = M - 1;
        const unsigned short* base = (tile == 0) ? Ahi : Alo;
        gsrc = base + (size_t)grow * K + k0 + cl * 8;
      } else {
        int gcol = bcol0 + row;
        const unsigned short* base = (tile == 2) ? Bhi : Blo;
        gsrc = base + (size_t)gcol * K + k0 + cl * 8;
      }
      unsigned short* ldst = &smem[(size_t)(tile * 512 + ((t & 1) << 8) + (tid & ~63)) * 8];
      __builtin_amdgcn_global_load_lds((const __attribute__((address_space(1))) void*)gsrc,
                                       (__attribute__((address_space(3))) void*)ldst, 16, 0, 0);
    }
    __syncthreads();

    bf16x8 ah[4], al[4];
#pragma unroll
    for (int mf = 0; mf < 4; mf++) {
      int R = wr * 64 + mf * 16 + (lane & 15);
      int off = R * 32 + ((((lane >> 4)) ^ ((R >> 1) & 3)) << 3);
      ah[mf] = *(const bf16x8*)&smem[off];
      al[mf] = *(const bf16x8*)&smem[4096 + off];
    }
#pragma unroll
    for (int nf = 0; nf < 4; nf++) {
      int R = wc * 64 + nf * 16 + (lane & 15);
      int off = R * 32 + ((((lane >> 4)) ^ ((R >> 1) & 3)) << 3);
      bf16x8 bh = *(const bf16x8*)&smem[8192 + off];
      bf16x8 bl = *(const bf16x8*)&smem[12288 + off];
#pragma unroll
      for (int mf = 0; mf < 4; mf++) {
        acc[mf][nf] = __builtin_amdgcn_mfma_f32_16x16x32_bf16(ah[mf], bh, acc[mf][nf], 0, 0, 0);
        acc[mf][nf] = __builtin_amdgcn_mfma_f32_16x16x32_bf16(al[mf], bh, acc[mf][nf], 0, 0, 0);
        acc[mf][nf] = __builtin_amdgcn_mfma_f32_16x16x32_bf16(ah[mf], bl, acc[mf][nf], 0, 0, 0);
      }
    }
    __syncthreads();
  }

  // epilogue: C/D layout col = lane&15, row = (lane>>4)*4 + reg (m89)
  const int orow = (lane >> 4) * 4;
  const int ocol = lane & 15;
#pragma unroll
  for (int mf = 0; mf < 4; mf++) {
#pragma unroll
    for (int r = 0; r < 4; r++) {
      int grow = brow0 + wr * 64 + mf * 16 + orow + r;
      if (grow < M) {
#pragma unroll
        for (int nf = 0; nf < 4; nf++) {
          int gcol = bcol0 + wc * 64 + nf * 16 + ocol;
          C[(size_t)grow * Ncols + gcol] = acc[mf][nf][r];
        }
      }
    }
  }
}

// ---------------- alpha_s / alpha_d: one wave per (node, head) ----------------
template <int H>
__global__ __launch_bounds__(256)
void alpha_kernel(const float* __restrict__ h, const float* __restrict__ a_s,
                  const float* __restrict__ a_d, float* __restrict__ as_out,
                  float* __restrict__ ad_out) {
  int gw = (blockIdx.x * blockDim.x + threadIdx.x) >> 6;
  int lane = threadIdx.x & 63;
  if (gw >= NN * H) return;
  int node = gw / H, hh = gw % H;
  const float2 hv = *(const float2*)&h[(size_t)node * (H * HIDC) + hh * HIDC + lane * 2];
  const float2 sv = *(const float2*)&a_s[hh * HIDC + lane * 2];
  const float2 dv = *(const float2*)&a_d[hh * HIDC + lane * 2];
  float ss = hv.x * sv.x + hv.y * sv.y;
  float sd = hv.x * dv.x + hv.y * dv.y;
#pragma unroll
  for (int off = 32; off; off >>= 1) {
    ss += __shfl_xor(ss, off);
    sd += __shfl_xor(sd, off);
  }
  if (lane == 0) {
    as_out[node * H + hh] = ss;
    ad_out[node * H + hh] = sd;
  }
}

// ---------------- per-dst-node softmax + weighted aggregation ----------------
template <int H, int CH, bool SPLIT, bool ELU>  // CH = H * HIDC
__global__ __launch_bounds__(256)
void aggregate_kernel(const float* __restrict__ h, const float* __restrict__ asb,
                      const float* __restrict__ adb, const int* __restrict__ indptr,
                      const int* __restrict__ csr_src, const float* __restrict__ bias,
                      float* __restrict__ outF, unsigned short* __restrict__ outHi,
                      unsigned short* __restrict__ outLo) {
  constexpr int F = CH / 64;  // floats per lane
  int node = (blockIdx.x * blockDim.x + threadIdx.x) >> 6;
  int lane = threadIdx.x & 63;
  if (node >= NN) return;
  int beg = indptr[node], end = indptr[node + 1];
  int deg = end - beg;
  float acc[F];
#pragma unroll
  for (int f = 0; f < F; f++) acc[f] = 0.f;

  if (deg > 0) {
    float adv[H];
#pragma unroll
    for (int hh = 0; hh < H; hh++) adv[hh] = adb[node * H + hh];
    float m[H];
#pragma unroll
    for (int hh = 0; hh < H; hh++) m[hh] = -1e30f;
    for (int i = lane; i < deg; i += 64) {
      int s = csr_src[beg + i];
#pragma unroll
      for (int hh = 0; hh < H; hh++) {
        float e = lrelu(asb[s * H + hh] + adv[hh]);
        m[hh] = fmaxf(m[hh], e);
      }
    }
#pragma unroll
    for (int off = 32; off; off >>= 1)
#pragma unroll
      for (int hh = 0; hh < H; hh++) m[hh] = fmaxf(m[hh], __shfl_xor(m[hh], off));
    float ssum[H];
#pragma unroll
    for (int hh = 0; hh < H; hh++) ssum[hh] = 0.f;
    for (int i = lane; i < deg; i += 64) {
      int s = csr_src[beg + i];
#pragma unroll
      for (int hh = 0; hh < H; hh++) {
        float e = lrelu(asb[s * H + hh] + adv[hh]);
        ssum[hh] += expf(e - m[hh]);
      }
    }
#pragma unroll
    for (int off = 32; off; off >>= 1)
#pragma unroll
      for (int hh = 0; hh < H; hh++) ssum[hh] += __shfl_xor(ssum[hh], off);
    float rden[H];
#pragma unroll
    for (int hh = 0; hh < H; hh++) rden[hh] = 1.f / (ssum[hh] + 1e-16f);

    const int myh = (lane * F) / HIDC;  // this lane's channels live in one head
    float myadv = adv[myh], mym = m[myh], myrd = rden[myh];
    for (int i = 0; i < deg; i++) {
      int s = csr_src[beg + i];
      float e = lrelu(asb[s * H + myh] + myadv);
      float w = expf(e - mym) * myrd;
      const float* hrow = &h[(size_t)s * CH + lane * F];
      if constexpr (F == 8) {
        float4 v0 = *(const float4*)&hrow[0];
        float4 v1 = *(const float4*)&hrow[4];
        acc[0] += w * v0.x; acc[1] += w * v0.y; acc[2] += w * v0.z; acc[3] += w * v0.w;
        acc[4] += w * v1.x; acc[5] += w * v1.y; acc[6] += w * v1.z; acc[7] += w * v1.w;
      } else {
        float2 v0 = *(const float2*)&hrow[0];
        acc[0] += w * v0.x;
        acc[1] += w * v0.y;
      }
    }
  }
  if constexpr (SPLIT) {
    unsigned short hs[F], ls[F];
#pragma unroll
    for (int f = 0; f < F; f++) {
      float v = acc[f] + bias[lane * F + f];
      if constexpr (ELU) v = v > 0.f ? v : expm1f(v);
      unsigned short hb = f2bf(v);
      hs[f] = hb;
      ls[f] = f2bf(v - bf2f(hb));
    }
    size_t o = (size_t)node * CH + lane * F;
    *(ushort4*)&outHi[o]     = make_ushort4(hs[0], hs[1], hs[2], hs[3]);
    *(ushort4*)&outHi[o + 4] = make_ushort4(hs[4], hs[5], hs[6], hs[7]);
    *(ushort4*)&outLo[o]     = make_ushort4(ls[0], ls[1], ls[2], ls[3]);
    *(ushort4*)&outLo[o + 4] = make_ushort4(ls[4], ls[5], ls[6], ls[7]);
  } else {
#pragma unroll
    for (int f = 0; f < F; f++) {
      int c = lane * F + f;
      float v = acc[f] + bias[c];
      if constexpr (ELU) v = v > 0.f ? v : expm1f(v);
      outF[(size_t)node * CH + c] = v;
    }
  }
}

// ---------------- global mean pool: two-phase deterministic reduction ----------------
__global__ void pool_partial(const float* __restrict__ node_emb, const int* __restrict__ batch,
                             float* __restrict__ part) {
  int g = blockIdx.x, chunk = blockIdx.y, c = threadIdx.x;
  int lo = 0, hi = NN;
  while (lo < hi) { int mid = (lo + hi) >> 1; if (batch[mid] < g) lo = mid + 1; else hi = mid; }
  int s = lo;
  lo = 0; hi = NN;
  while (lo < hi) { int mid = (lo + hi) >> 1; if (batch[mid] < g + 1) lo = mid + 1; else hi = mid; }
  int e = lo;
  int per = (e - s + POOL_CHUNKS - 1) / POOL_CHUNKS;
  int cs = s + chunk * per;
  int ce = cs + per; if (ce > e) ce = e;
  float sum = 0.f;
  for (int i = cs; i < ce; i++) sum += node_emb[(size_t)i * HIDC + c];
  part[((size_t)chunk * NGRAPH + g) * HIDC + c] = sum;
}

__global__ void pool_final(const float* __restrict__ part, const int* __restrict__ batch,
                           float* __restrict__ gout) {
  int g = blockIdx.x, c = threadIdx.x;
  int lo = 0, hi = NN;
  while (lo < hi) { int mid = (lo + hi) >> 1; if (batch[mid] < g) lo = mid + 1; else hi = mid; }
  int s = lo;
  lo = 0; hi = NN;
  while (lo < hi) { int mid = (lo + hi) >> 1; if (batch[mid] < g + 1) lo = mid + 1; else hi = mid; }
  int e = lo;
  float sum = 0.f;
#pragma unroll
  for (int k = 0; k < POOL_CHUNKS; k++) sum += part[((size_t)k * NGRAPH + g) * HIDC + c];
  gout[g * HIDC + c] = sum / fmaxf((float)(e - s), 1.0f);
}

extern "C" void kernel_launch(void* const* d_in, const int* in_sizes, int n_in,
                              void* d_out, int out_size, void* d_ws, size_t ws_size,
                              hipStream_t stream) {
  const float* x   = (const float*)d_in[0];
  const int* ei    = (const int*)d_in[1];
  const int* batch = (const int*)d_in[2];
  const float* W1  = (const float*)d_in[3];
  const float* a1s = (const float*)d_in[4];
  const float* a1d = (const float*)d_in[5];
  const float* b1  = (const float*)d_in[6];
  const float* W2  = (const float*)d_in[7];
  const float* a2s = (const float*)d_in[8];
  const float* a2d = (const float*)d_in[9];
  const float* b2  = (const float*)d_in[10];
  const float* W3  = (const float*)d_in[11];
  const float* a3s = (const float*)d_in[12];
  const float* a3d = (const float*)d_in[13];
  const float* b3  = (const float*)d_in[14];
  float* out_node  = (float*)d_out;
  float* out_graph = out_node + (size_t)NN * HIDC;

  char* p = (char*)d_ws;
  auto take = [&](size_t bytes) {
    char* cur = p;
    p += (bytes + 255) & ~(size_t)255;
    return cur;
  };
  unsigned short* hHi = (unsigned short*)take((size_t)NN * 512 * 2);
  unsigned short* hLo = (unsigned short*)take((size_t)NN * 512 * 2);
  float* bufF = (float*)take((size_t)NN * 512 * 4);
  float* asb  = (float*)take((size_t)NN * 4 * 4);
  float* adb  = (float*)take((size_t)NN * 4 * 4);
  unsigned short* W1tH = (unsigned short*)take((size_t)512 * 256 * 2);
  unsigned short* W1tL = (unsigned short*)take((size_t)512 * 256 * 2);
  unsigned short* W2tH = (unsigned short*)take((size_t)512 * 512 * 2);
  unsigned short* W2tL = (unsigned short*)take((size_t)512 * 512 * 2);
  unsigned short* W3tH = (unsigned short*)take((size_t)128 * 512 * 2);
  unsigned short* W3tL = (unsigned short*)take((size_t)128 * 512 * 2);
  int* deg    = (int*)take((size_t)NN * 4);
  int* indptr = (int*)take((size_t)(NN + 1) * 4);
  int* cursor = (int*)take((size_t)NN * 4);
  int* csr    = (int*)take((size_t)EE * 4);
  float* poolws = (float*)take((size_t)POOL_CHUNKS * NGRAPH * HIDC * 4);

  const int* srcv = ei;
  const int* dstv = ei + EE;

  // CSR build
  hipMemsetAsync(deg, 0, (size_t)NN * 4, stream);
  hist_kernel<<<(EE + 255) / 256, 256, 0, stream>>>(dstv, deg);
  scan_kernel<<<1, 1024, 0, stream>>>(deg, indptr, cursor);
  scatter_kernel<<<(EE + 255) / 256, 256, 0, stream>>>(srcv, dstv, cursor, csr);

  // weight transpose + split; x split (x_hi/x_lo alias hHi/hLo — dead before aggregate1 writes)
  transpose_split<<<dim3(512 / 32, 256 / 32), 256, 0, stream>>>(W1, W1tH, W1tL, 256, 512);
  transpose_split<<<dim3(512 / 32, 512 / 32), 256, 0, stream>>>(W2, W2tH, W2tL, 512, 512);
  transpose_split<<<dim3(128 / 32, 512 / 32), 256, 0, stream>>>(W3, W3tH, W3tL, 512, 128);
  split_x<<<(NN * FIN / 4 + 255) / 256, 256, 0, stream>>>(x, hHi, hLo, NN * FIN / 4);

  dim3 blk(256);
  const int rowBlocks = (NN + 127) / 128;
  // layer 1
  gemm_split<<<dim3(4, rowBlocks), blk, 0, stream>>>(hHi, hLo, W1tH, W1tL, bufF, NN, 256, 512);
  alpha_kernel<4><<<(NN * 4 + 3) / 4, blk, 0, stream>>>(bufF, a1s, a1d, asb, adb);
  aggregate_kernel<4, 512, true, true><<<(NN + 3) / 4, blk, 0, stream>>>(
      bufF, asb, adb, indptr, csr, b1, nullptr, hHi, hLo);
  // layer 2
  gemm_split<<<dim3(4, rowBlocks), blk, 0, stream>>>(hHi, hLo, W2tH, W2tL, bufF, NN, 512, 512);
  alpha_kernel<4><<<(NN * 4 + 3) / 4, blk, 0, stream>>>(bufF, a2s, a2d, asb, adb);
  aggregate_kernel<4, 512, true, true><<<(NN + 3) / 4, blk, 0, stream>>>(
      bufF, asb, adb, indptr, csr, b2, nullptr, hHi, hLo);
  // layer 3
  gemm_split<<<dim3(1, rowBlocks), blk, 0, stream>>>(hHi, hLo, W3tH, W3tL, bufF, NN, 512, 128);
  alpha_kernel<1><<<(NN + 3) / 4, blk, 0, stream>>>(bufF, a3s, a3d, asb, adb);
  aggregate_kernel<1, 128, false, false><<<(NN + 3) / 4, blk, 0, stream>>>(
      bufF, asb, adb, indptr, csr, b3, out_node, nullptr, nullptr);
  // per-graph mean pool (two-phase, deterministic)
  pool_partial<<<dim3(NGRAPH, POOL_CHUNKS), HIDC, 0, stream>>>(out_node, batch, poolws);
  pool_final<<<NGRAPH, HIDC, 0, stream>>>(poolws, batch, out_graph);
}